// Round 4
// baseline (407.288 us; speedup 1.0000x reference)
//
#include <hip/hip_runtime.h>
#include <hip/hip_bf16.h>
#include <stdint.h>

#define K_D 512
#define N_C 100000
#define SCALE 64.0f

// margin constants (double-precision derived)
#define COS_M 0.87758256189037271612f
#define SIN_M 0.47942553860420300027f
#define TH   (-0.87758256189037271612f)
#define MM_C  0.23971276930210150013f

typedef __attribute__((ext_vector_type(8))) short bf16x8;
typedef __attribute__((ext_vector_type(4))) float f32x4;

#define NB 1563          // ceil(100000/64) class blocks
#define ZSTRIDE 1568

// ws byte offsets (total 1,875,968 — within proven ws capacity >= 1,879,040)
#define OFF_INVNE 0          // 256 f
#define OFF_EMB   1024       // 256*512 ushorts = 262144 (fragment-ordered)
#define OFF_TP    263168     // 768*2 f
#define OFF_ZROW  269312     // 256 f
#define OFF_ZPART 270336     // 256*1568 f = 1,605,632

__device__ __forceinline__ ushort f2bf(float f) {
    __hip_bfloat16 h = __float2bfloat16(f);
    return __builtin_bit_cast(ushort, h);
}

// ---------------- prep_emb: fragment-ordered bf16 copy of E + inv row norms ----
// Ebf slot = ((row>>4)*16 + ks)*64 + (row&15) + g*16  (8 ushorts per slot), so
// gemm's A-load for (m-tile, ks) is one coalesced 1KB b128 load per wave.
__global__ __launch_bounds__(256) void prep_emb(const float* __restrict__ E,
                                                ushort* __restrict__ Ebf,
                                                float* __restrict__ invne) {
    int w = threadIdx.x >> 6, lane = threadIdx.x & 63;
    int row = blockIdx.x * 4 + w;
    const float4* src = (const float4*)(E + (size_t)row * K_D);
    float4 a = src[2 * lane];          // k = lane*8 .. +4
    float4 b = src[2 * lane + 1];      // k = lane*8+4 .. +8
    float ss = a.x*a.x + a.y*a.y + a.z*a.z + a.w*a.w
             + b.x*b.x + b.y*b.y + b.z*b.z + b.w*b.w;
    #pragma unroll
    for (int m = 32; m >= 1; m >>= 1) ss += __shfl_xor(ss, m, 64);
    uint4 pk;
    pk.x = (uint32_t)f2bf(a.x) | ((uint32_t)f2bf(a.y) << 16);
    pk.y = (uint32_t)f2bf(a.z) | ((uint32_t)f2bf(a.w) << 16);
    pk.z = (uint32_t)f2bf(b.x) | ((uint32_t)f2bf(b.y) << 16);
    pk.w = (uint32_t)f2bf(b.z) | ((uint32_t)f2bf(b.w) << 16);
    const int kstep = lane >> 2, gg = lane & 3;
    const size_t slot = ((size_t)(row >> 4) * 16 + kstep) * 64 + (row & 15) + (gg << 4);
    ((uint4*)Ebf)[slot] = pk;
    if (lane == 0) invne[row] = rsqrtf(ss + 1e-12f);
}

// ---------------- threefry2x32 (JAX, key=42) ----------------
__device__ __forceinline__ void threefry(uint32_t x0, uint32_t x1, uint32_t& o0, uint32_t& o1) {
    const uint32_t k0 = 0u, k1 = 42u;
    const uint32_t k2 = k0 ^ k1 ^ 0x1BD11BDAu;
    const uint32_t ks[3] = {k0, k1, k2};
    x0 += k0; x1 += k1;
    const int rot0[4] = {13, 15, 26, 6};
    const int rot1[4] = {17, 29, 16, 24};
    #pragma unroll
    for (int grp = 0; grp < 5; ++grp) {
        const int* r = (grp & 1) ? rot1 : rot0;
        #pragma unroll
        for (int i = 0; i < 4; ++i) {
            x0 += x1;
            x1 = (x1 << r[i]) | (x1 >> (32 - r[i]));
            x1 ^= x0;
        }
        x0 += ks[(grp + 1) % 3];
        x1 += ks[(grp + 2) % 3] + (uint32_t)(grp + 1);
    }
    o0 = x0; o1 = x1;
}

// ---------------- targets: inline label shuffle + precise fp32 cosine + margin ----
__global__ __launch_bounds__(256) void target_kernel(const float* __restrict__ E,
                                                     const float* __restrict__ W,
                                                     const int* __restrict__ ll,
                                                     float* __restrict__ tp) {
    int w = threadIdx.x >> 6, lane = threadIdx.x & 63;
    int p = blockIdx.x * 4 + w;      // 768 pairs
    int b = p / 3;
    int jj = p - b * 3;
    float u[8];
    #pragma unroll
    for (int j = 0; j < 8; ++j) {
        int n = b * 8 + j;
        uint32_t x0, x1, o0, o1;
        if (n < 1024) { x0 = (uint32_t)n; x1 = (uint32_t)(n + 1024); }
        else          { x0 = (uint32_t)(n - 1024); x1 = (uint32_t)n; }
        threefry(x0, x1, o0, o1);
        uint32_t bits = (n < 1024) ? o0 : o1;
        uint32_t fb = (bits >> 9) | 0x3F800000u;
        u[j] = __builtin_bit_cast(float, fb) - 1.0f;
    }
    bool used[8] = {false,false,false,false,false,false,false,false};
    int sel = 0;
    for (int s = 0; s <= jj; ++s) {
        float bv = 2.0f; int bi = 0;
        for (int i = 0; i < 8; ++i)
            if (!used[i] && u[i] < bv) { bv = u[i]; bi = i; }
        used[bi] = true;
        sel = bi;
    }
    int c = ll[b * 8 + sel];

    const float4* ep = (const float4*)(E + (size_t)b * K_D);
    const float4* wp = (const float4*)(W + (size_t)c * K_D);
    float4 e0 = ep[lane], e1 = ep[lane + 64];
    float4 w0 = wp[lane], w1 = wp[lane + 64];
    float dot = e0.x*w0.x + e0.y*w0.y + e0.z*w0.z + e0.w*w0.w
              + e1.x*w1.x + e1.y*w1.y + e1.z*w1.z + e1.w*w1.w;
    float esq = e0.x*e0.x + e0.y*e0.y + e0.z*e0.z + e0.w*e0.w
              + e1.x*e1.x + e1.y*e1.y + e1.z*e1.z + e1.w*e1.w;
    float wsq = w0.x*w0.x + w0.y*w0.y + w0.z*w0.z + w0.w*w0.w
              + w1.x*w1.x + w1.y*w1.y + w1.z*w1.z + w1.w*w1.w;
    #pragma unroll
    for (int m = 32; m >= 1; m >>= 1) {
        dot += __shfl_xor(dot, m, 64);
        esq += __shfl_xor(esq, m, 64);
        wsq += __shfl_xor(wsq, m, 64);
    }
    if (lane == 0) {
        float t = dot * rsqrtf(esq + 1e-12f) * rsqrtf(wsq + 1e-12f);
        t = fminf(1.0f, fmaxf(-1.0f, t));
        float tc = fminf(1.0f - 1e-7f, fmaxf(-1.0f + 1e-7f, t));
        float marg = tc * COS_M - sqrtf(fmaxf(0.0f, 1.0f - tc * tc)) * SIN_M;
        float ft = (t > TH) ? marg : (t - MM_C);
        tp[p * 2]     = t;
        tp[p * 2 + 1] = ft;
    }
}

// ---------------- fused GEMM + exp-sum: all-register, no LDS, no drains -------
// grid 1563, block 256 (4 waves). Wave wq: M=64 rows (m-tiles wq*4..+3) x N=64
// classes. Per ks: 8 independent dwordx4 W loads + 4 coalesced b128 A loads
// per lane — ILP+TLP latency hiding, W read once per block from HBM (4x from
// L2 across the block's waves, kept hot by drain-free s_barrier every 4 ks).
__global__ __launch_bounds__(256, 3) void gemm_z(const float* __restrict__ W,
                                                 const ushort* __restrict__ Ebf,
                                                 const float* __restrict__ invne,
                                                 float* __restrict__ zpart) {
    const int tid  = threadIdx.x;
    const int lane = tid & 63, wq = tid >> 6;
    const int r16  = lane & 15, g = lane >> 4;
    const int bx   = blockIdx.x;
    const int c0   = bx * 64;

    // per-n W row base (clamped for the tail block)
    const float* wb[4];
    int cls[4];
    #pragma unroll
    for (int n = 0; n < 4; ++n) {
        int c = c0 + n * 16 + r16;
        cls[n] = c;
        int cc = c < N_C ? c : N_C - 1;
        wb[n] = W + (size_t)cc * K_D + g * 8;
    }
    const ushort* ab = Ebf + (size_t)(wq * 4) * 8192 + lane * 8;

    f32x4 acc[4][4] = {};   // [m][n]
    float ssq[4] = {0.f, 0.f, 0.f, 0.f};

    #pragma unroll 4
    for (int ks = 0; ks < 16; ++ks) {
        bf16x8 a[4];
        #pragma unroll
        for (int m = 0; m < 4; ++m)
            a[m] = *(const bf16x8*)(ab + (size_t)m * 8192 + ks * 512);
        #pragma unroll
        for (int n = 0; n < 4; ++n) {
            float4 f0 = *(const float4*)(wb[n] + ks * 32);
            float4 f1 = *(const float4*)(wb[n] + ks * 32 + 4);
            ssq[n] += f0.x*f0.x + f0.y*f0.y + f0.z*f0.z + f0.w*f0.w
                    + f1.x*f1.x + f1.y*f1.y + f1.z*f1.z + f1.w*f1.w;
            bf16x8 bv;
            bv[0] = (short)f2bf(f0.x); bv[1] = (short)f2bf(f0.y);
            bv[2] = (short)f2bf(f0.z); bv[3] = (short)f2bf(f0.w);
            bv[4] = (short)f2bf(f1.x); bv[5] = (short)f2bf(f1.y);
            bv[6] = (short)f2bf(f1.z); bv[7] = (short)f2bf(f1.w);
            #pragma unroll
            for (int m = 0; m < 4; ++m)
                acc[m][n] = __builtin_amdgcn_mfma_f32_16x16x32_bf16(a[m], bv, acc[m][n], 0, 0, 0);
        }
        // keep the block's waves in lockstep (raw barrier: NO waitcnt drain)
        if (((ks & 3) == 3) && ks < 15) __builtin_amdgcn_s_barrier();
    }

    // class inverse norms: reduce ssq over the 4 g-groups
    float inw[4];
    #pragma unroll
    for (int n = 0; n < 4; ++n) {
        float s = ssq[n];
        s += __shfl_xor(s, 16, 64);
        s += __shfl_xor(s, 32, 64);
        inw[n] = rsqrtf(s + 1e-12f);
    }

    // epilogue: cos -> exp(64 cos - 64); reduce over 64 classes; write zpart
    #pragma unroll
    for (int m = 0; m < 4; ++m) {
        #pragma unroll
        for (int i = 0; i < 4; ++i) {
            const int row = (wq * 4 + m) * 16 + g * 4 + i;
            const float ine = invne[row];
            float s = 0.f;
            #pragma unroll
            for (int n = 0; n < 4; ++n) {
                float cv = acc[m][n][i] * inw[n] * ine;
                cv = fminf(1.0f, fmaxf(-1.0f, cv));
                float e = __expf(SCALE * cv - 64.0f);
                if (cls[n] < N_C) s += e;
            }
            s += __shfl_xor(s, 1, 64);
            s += __shfl_xor(s, 2, 64);
            s += __shfl_xor(s, 4, 64);
            s += __shfl_xor(s, 8, 64);
            if (r16 == m * 4 + i) zpart[(size_t)row * ZSTRIDE + bx] = s;
        }
    }
}

// ---------------- per-row Z reduction (coalesced) ----------------
__global__ __launch_bounds__(256) void zrow_kernel(const float* __restrict__ zpart,
                                                   float* __restrict__ zrow) {
    const int b = blockIdx.x;
    float sum = 0.f;
    for (int t = threadIdx.x; t < NB; t += 256)
        sum += zpart[(size_t)b * ZSTRIDE + t];
    __shared__ float red[256];
    red[threadIdx.x] = sum;
    __syncthreads();
    for (int st = 128; st >= 1; st >>= 1) {
        if (threadIdx.x < st) red[threadIdx.x] += red[threadIdx.x + st];
        __syncthreads();
    }
    if (threadIdx.x == 0) zrow[b] = red[0];
}

// ---------------- final loss ----------------
__global__ __launch_bounds__(256) void loss_kernel(const float* __restrict__ zrow,
                                                   const float* __restrict__ tp,
                                                   float* __restrict__ out) {
    const int b = threadIdx.x;
    const float Z = zrow[b];
    float lsum = 0.f;
    #pragma unroll
    for (int j = 0; j < 3; ++j) {
        float t  = tp[(b * 3 + j) * 2];
        float ft = tp[(b * 3 + j) * 2 + 1];
        float S = Z - expf(SCALE * t - 64.0f) + expf(SCALE * ft - 64.0f);
        lsum += logf(S) + 64.0f - SCALE * ft;
    }
    __shared__ float red[256];
    red[b] = lsum;
    __syncthreads();
    for (int st = 128; st >= 1; st >>= 1) {
        if (b < st) red[b] += red[b + st];
        __syncthreads();
    }
    if (b == 0) out[0] = red[0] / 768.0f;
}

extern "C" void kernel_launch(void* const* d_in, const int* in_sizes, int n_in,
                              void* d_out, int out_size, void* d_ws, size_t ws_size,
                              hipStream_t stream) {
    const float* E = (const float*)d_in[0];
    const float* W = (const float*)d_in[1];
    const int*  LL = (const int*)d_in[2];
    char* ws = (char*)d_ws;
    float*  invne = (float*)(ws + OFF_INVNE);
    ushort* Ebf   = (ushort*)(ws + OFF_EMB);
    float*  tp    = (float*)(ws + OFF_TP);
    float*  zrow  = (float*)(ws + OFF_ZROW);
    float*  zpart = (float*)(ws + OFF_ZPART);
    float*  out   = (float*)d_out;

    hipLaunchKernelGGL(prep_emb,      dim3(64),   dim3(256), 0, stream, E, Ebf, invne);
    hipLaunchKernelGGL(target_kernel, dim3(192),  dim3(256), 0, stream, E, W, LL, tp);
    hipLaunchKernelGGL(gemm_z,        dim3(NB),   dim3(256), 0, stream, W, Ebf, invne, zpart);
    hipLaunchKernelGGL(zrow_kernel,   dim3(256),  dim3(256), 0, stream, zpart, zrow);
    hipLaunchKernelGGL(loss_kernel,   dim3(1),    dim3(256), 0, stream, zrow, tp, out);
}

// Round 5
// 142.559 us; speedup vs baseline: 2.8570x; 2.8570x over previous
//
#include <hip/hip_runtime.h>
#include <hip/hip_bf16.h>
#include <stdint.h>

#define K_D 512
#define N_C 100000
#define SCALE 64.0f

// margin constants (double-precision derived)
#define COS_M 0.87758256189037271612f
#define SIN_M 0.47942553860420300027f
#define TH   (-0.87758256189037271612f)
#define MM_C  0.23971276930210150013f

typedef __attribute__((ext_vector_type(8))) short bf16x8;
typedef __attribute__((ext_vector_type(4))) float f32x4;

#define NNB 782          // n-blocks of 128 classes (782*128 = 100096)
#define NMB 4            // m-blocks of 64 rows
#define GZ_GRID 3128     // 782*4 = 8 XCDs x 391 exactly (bijective swizzle)
#define ZSTRIDE 784

// ws byte offsets (total 1,073,152 — within proven ws capacity >= 1,879,040)
#define OFF_INVNE 0          // 256 f
#define OFF_EMB   1024       // 256*512 ushorts = 262144 (fragment-ordered)
#define OFF_TP    263168     // 768*2 f
#define OFF_ZROW  269312     // 256 f
#define OFF_ZPART 270336     // 256*784 f = 802,816

__device__ __forceinline__ ushort f2bf(float f) {
    __hip_bfloat16 h = __float2bfloat16(f);
    return __builtin_bit_cast(ushort, h);
}

__device__ __forceinline__ void async16(const void* src, void* dst) {
    __builtin_amdgcn_global_load_lds(
        (const __attribute__((address_space(1))) void*)src,
        (__attribute__((address_space(3))) void*)dst,
        16, 0, 0);
}

// ---------------- prep_emb: fragment-ordered bf16 copy of E + inv row norms ----
// Ebf slot = ((row>>4)*16 + ks)*64 + (row&15) + g*16  (8 ushorts per slot):
// the A-frag load for (m-tile, ks) is one coalesced 1KB b128 load per wave.
__global__ __launch_bounds__(256) void prep_emb(const float* __restrict__ E,
                                                ushort* __restrict__ Ebf,
                                                float* __restrict__ invne) {
    int w = threadIdx.x >> 6, lane = threadIdx.x & 63;
    int row = blockIdx.x * 4 + w;
    const float4* src = (const float4*)(E + (size_t)row * K_D);
    float4 a = src[2 * lane];          // k = lane*8 .. +4
    float4 b = src[2 * lane + 1];      // k = lane*8+4 .. +8
    float ss = a.x*a.x + a.y*a.y + a.z*a.z + a.w*a.w
             + b.x*b.x + b.y*b.y + b.z*b.z + b.w*b.w;
    #pragma unroll
    for (int m = 32; m >= 1; m >>= 1) ss += __shfl_xor(ss, m, 64);
    uint4 pk;
    pk.x = (uint32_t)f2bf(a.x) | ((uint32_t)f2bf(a.y) << 16);
    pk.y = (uint32_t)f2bf(a.z) | ((uint32_t)f2bf(a.w) << 16);
    pk.z = (uint32_t)f2bf(b.x) | ((uint32_t)f2bf(b.y) << 16);
    pk.w = (uint32_t)f2bf(b.z) | ((uint32_t)f2bf(b.w) << 16);
    const int kstep = lane >> 2, gg = lane & 3;
    const size_t slot = ((size_t)(row >> 4) * 16 + kstep) * 64 + (row & 15) + (gg << 4);
    ((uint4*)Ebf)[slot] = pk;
    if (lane == 0) invne[row] = rsqrtf(ss + 1e-12f);
}

// ---------------- threefry2x32 (JAX, key=42) ----------------
__device__ __forceinline__ void threefry(uint32_t x0, uint32_t x1, uint32_t& o0, uint32_t& o1) {
    const uint32_t k0 = 0u, k1 = 42u;
    const uint32_t k2 = k0 ^ k1 ^ 0x1BD11BDAu;
    const uint32_t ks[3] = {k0, k1, k2};
    x0 += k0; x1 += k1;
    const int rot0[4] = {13, 15, 26, 6};
    const int rot1[4] = {17, 29, 16, 24};
    #pragma unroll
    for (int grp = 0; grp < 5; ++grp) {
        const int* r = (grp & 1) ? rot1 : rot0;
        #pragma unroll
        for (int i = 0; i < 4; ++i) {
            x0 += x1;
            x1 = (x1 << r[i]) | (x1 >> (32 - r[i]));
            x1 ^= x0;
        }
        x0 += ks[(grp + 1) % 3];
        x1 += ks[(grp + 2) % 3] + (uint32_t)(grp + 1);
    }
    o0 = x0; o1 = x1;
}

// ---------------- targets: inline label shuffle + precise fp32 cosine + margin ----
__global__ __launch_bounds__(256) void target_kernel(const float* __restrict__ E,
                                                     const float* __restrict__ W,
                                                     const int* __restrict__ ll,
                                                     float* __restrict__ tp) {
    int w = threadIdx.x >> 6, lane = threadIdx.x & 63;
    int p = blockIdx.x * 4 + w;      // 768 pairs
    int b = p / 3;
    int jj = p - b * 3;
    float u[8];
    #pragma unroll
    for (int j = 0; j < 8; ++j) {
        int n = b * 8 + j;
        uint32_t x0, x1, o0, o1;
        if (n < 1024) { x0 = (uint32_t)n; x1 = (uint32_t)(n + 1024); }
        else          { x0 = (uint32_t)(n - 1024); x1 = (uint32_t)n; }
        threefry(x0, x1, o0, o1);
        uint32_t bits = (n < 1024) ? o0 : o1;
        uint32_t fb = (bits >> 9) | 0x3F800000u;
        u[j] = __builtin_bit_cast(float, fb) - 1.0f;
    }
    bool used[8] = {false,false,false,false,false,false,false,false};
    int sel = 0;
    for (int s = 0; s <= jj; ++s) {
        float bv = 2.0f; int bi = 0;
        for (int i = 0; i < 8; ++i)
            if (!used[i] && u[i] < bv) { bv = u[i]; bi = i; }
        used[bi] = true;
        sel = bi;
    }
    int c = ll[b * 8 + sel];

    const float4* ep = (const float4*)(E + (size_t)b * K_D);
    const float4* wp = (const float4*)(W + (size_t)c * K_D);
    float4 e0 = ep[lane], e1 = ep[lane + 64];
    float4 w0 = wp[lane], w1 = wp[lane + 64];
    float dot = e0.x*w0.x + e0.y*w0.y + e0.z*w0.z + e0.w*w0.w
              + e1.x*w1.x + e1.y*w1.y + e1.z*w1.z + e1.w*w1.w;
    float esq = e0.x*e0.x + e0.y*e0.y + e0.z*e0.z + e0.w*e0.w
              + e1.x*e1.x + e1.y*e1.y + e1.z*e1.z + e1.w*e1.w;
    float wsq = w0.x*w0.x + w0.y*w0.y + w0.z*w0.z + w0.w*w0.w
              + w1.x*w1.x + w1.y*w1.y + w1.z*w1.z + w1.w*w1.w;
    #pragma unroll
    for (int m = 32; m >= 1; m >>= 1) {
        dot += __shfl_xor(dot, m, 64);
        esq += __shfl_xor(esq, m, 64);
        wsq += __shfl_xor(wsq, m, 64);
    }
    if (lane == 0) {
        float t = dot * rsqrtf(esq + 1e-12f) * rsqrtf(wsq + 1e-12f);
        t = fminf(1.0f, fmaxf(-1.0f, t));
        float tc = fminf(1.0f - 1e-7f, fmaxf(-1.0f + 1e-7f, t));
        float marg = tc * COS_M - sqrtf(fmaxf(0.0f, 1.0f - tc * tc)) * SIN_M;
        float ft = (t > TH) ? marg : (t - MM_C);
        tp[p * 2]     = t;
        tp[p * 2 + 1] = ft;
    }
}

// ---------------- fused GEMM + exp-sum ----------------
// 512 thr / 8 waves. Block tile: M=64 rows x N=128 classes; wave = M=64 x N=16
// (acc[4] only). A staged once in LDS (64 KB, linear DMA); W streamed straight
// to registers with 1-deep prefetch, ZERO barriers in the K-loop. Bijective
// XCD swizzle (3128 = 8 x 391) keeps the 4 m-blocks of one n-column on the
// same XCD so W leaves HBM once and replays hit that XCD's L2.
__global__ __launch_bounds__(512, 2) void gemm_z(const float* __restrict__ W,
                                                 const ushort* __restrict__ Ebf,
                                                 const float* __restrict__ invne,
                                                 float* __restrict__ zpart) {
    __shared__ ushort Als[64 * 512];   // 64 KB, fragment-ordered
    __shared__ float zred[64 * 8];

    const int tid  = threadIdx.x;
    const int lane = tid & 63, wv = tid >> 6;   // wv 0..7
    const int r16  = lane & 15, g = lane >> 4;

    const int wid = (blockIdx.x & 7) * 391 + (blockIdx.x >> 3);
    const int nb  = wid >> 2;          // 0..781
    const int mb  = wid & 3;           // 0..3
    const int c0  = nb * 128;
    const int r0  = mb * 64;

    // stage A: 64 KB linear from Ebf (frag-ordered; rows r0..r0+63 contiguous)
    {
        const ushort* src = Ebf + (size_t)r0 * K_D + (size_t)wv * (8 * 512) + lane * 8;
        #pragma unroll
        for (int t = 0; t < 8; ++t)
            async16(src + t * 512, &Als[(wv * 8 + t) * 512]);
    }
    __syncthreads();

    const int ccls = c0 + wv * 16 + r16;               // this lane's class
    const int ccl  = ccls < N_C ? ccls : N_C - 1;
    const float* wrow = W + (size_t)ccl * K_D + g * 8;

    f32x4 acc[4] = {};
    float ssq = 0.f;

    float4 nf0 = *(const float4*)(wrow);
    float4 nf1 = *(const float4*)(wrow + 4);
    #pragma unroll
    for (int ks = 0; ks < 16; ++ks) {
        float4 f0 = nf0, f1 = nf1;
        if (ks < 15) {
            nf0 = *(const float4*)(wrow + (ks + 1) * 32);
            nf1 = *(const float4*)(wrow + (ks + 1) * 32 + 4);
        }
        ssq += f0.x*f0.x + f0.y*f0.y + f0.z*f0.z + f0.w*f0.w
             + f1.x*f1.x + f1.y*f1.y + f1.z*f1.z + f1.w*f1.w;
        bf16x8 bv;
        bv[0] = (short)f2bf(f0.x); bv[1] = (short)f2bf(f0.y);
        bv[2] = (short)f2bf(f0.z); bv[3] = (short)f2bf(f0.w);
        bv[4] = (short)f2bf(f1.x); bv[5] = (short)f2bf(f1.y);
        bv[6] = (short)f2bf(f1.z); bv[7] = (short)f2bf(f1.w);
        #pragma unroll
        for (int mt = 0; mt < 4; ++mt) {
            bf16x8 a = *(const bf16x8*)&Als[(size_t)(mt * 16 + ks) * 512 + lane * 8];
            acc[mt] = __builtin_amdgcn_mfma_f32_16x16x32_bf16(a, bv, acc[mt], 0, 0, 0);
        }
    }

    // class inverse norm: reduce ssq over the 4 g-groups (same class)
    float sr = ssq;
    sr += __shfl_xor(sr, 16, 64);
    sr += __shfl_xor(sr, 32, 64);
    const float inw = rsqrtf(sr + 1e-12f);
    const bool valid = ccls < N_C;

    // epilogue: cos -> exp(64cos-64); reduce over this wave's 16 classes
    #pragma unroll
    for (int mt = 0; mt < 4; ++mt) {
        #pragma unroll
        for (int i = 0; i < 4; ++i) {
            const int rloc = mt * 16 + g * 4 + i;      // 0..63
            float cv = acc[mt][i] * inw * invne[r0 + rloc];
            cv = fminf(1.0f, fmaxf(-1.0f, cv));
            float s = valid ? __expf(SCALE * cv - 64.0f) : 0.f;
            s += __shfl_xor(s, 1, 64);
            s += __shfl_xor(s, 2, 64);
            s += __shfl_xor(s, 4, 64);
            s += __shfl_xor(s, 8, 64);
            if (r16 == 0) zred[rloc * 8 + wv] = s;
        }
    }
    __syncthreads();
    // cross-wave: 64 rows x 8 wave-partials, deterministic order
    if (tid < 64) {
        float t = 0.f;
        #pragma unroll
        for (int v = 0; v < 8; ++v) t += zred[tid * 8 + v];
        zpart[(size_t)(r0 + tid) * ZSTRIDE + nb] = t;
    }
}

// ---------------- per-row Z reduction (coalesced) ----------------
__global__ __launch_bounds__(256) void zrow_kernel(const float* __restrict__ zpart,
                                                   float* __restrict__ zrow) {
    const int b = blockIdx.x;
    float sum = 0.f;
    for (int t = threadIdx.x; t < NNB; t += 256)
        sum += zpart[(size_t)b * ZSTRIDE + t];
    __shared__ float red[256];
    red[threadIdx.x] = sum;
    __syncthreads();
    for (int st = 128; st >= 1; st >>= 1) {
        if (threadIdx.x < st) red[threadIdx.x] += red[threadIdx.x + st];
        __syncthreads();
    }
    if (threadIdx.x == 0) zrow[b] = red[0];
}

// ---------------- final loss ----------------
__global__ __launch_bounds__(256) void loss_kernel(const float* __restrict__ zrow,
                                                   const float* __restrict__ tp,
                                                   float* __restrict__ out) {
    const int b = threadIdx.x;
    const float Z = zrow[b];
    float lsum = 0.f;
    #pragma unroll
    for (int j = 0; j < 3; ++j) {
        float t  = tp[(b * 3 + j) * 2];
        float ft = tp[(b * 3 + j) * 2 + 1];
        float S = Z - expf(SCALE * t - 64.0f) + expf(SCALE * ft - 64.0f);
        lsum += logf(S) + 64.0f - SCALE * ft;
    }
    __shared__ float red[256];
    red[b] = lsum;
    __syncthreads();
    for (int st = 128; st >= 1; st >>= 1) {
        if (b < st) red[b] += red[b + st];
        __syncthreads();
    }
    if (b == 0) out[0] = red[0] / 768.0f;
}

extern "C" void kernel_launch(void* const* d_in, const int* in_sizes, int n_in,
                              void* d_out, int out_size, void* d_ws, size_t ws_size,
                              hipStream_t stream) {
    const float* E = (const float*)d_in[0];
    const float* W = (const float*)d_in[1];
    const int*  LL = (const int*)d_in[2];
    char* ws = (char*)d_ws;
    float*  invne = (float*)(ws + OFF_INVNE);
    ushort* Ebf   = (ushort*)(ws + OFF_EMB);
    float*  tp    = (float*)(ws + OFF_TP);
    float*  zrow  = (float*)(ws + OFF_ZROW);
    float*  zpart = (float*)(ws + OFF_ZPART);
    float*  out   = (float*)d_out;

    hipLaunchKernelGGL(prep_emb,      dim3(64),      dim3(256), 0, stream, E, Ebf, invne);
    hipLaunchKernelGGL(target_kernel, dim3(192),     dim3(256), 0, stream, E, W, LL, tp);
    hipLaunchKernelGGL(gemm_z,        dim3(GZ_GRID), dim3(512), 0, stream, W, Ebf, invne, zpart);
    hipLaunchKernelGGL(zrow_kernel,   dim3(256),     dim3(256), 0, stream, zpart, zrow);
    hipLaunchKernelGGL(loss_kernel,   dim3(1),       dim3(256), 0, stream, zrow, tp, out);
}

// Round 6
// 142.018 us; speedup vs baseline: 2.8679x; 1.0038x over previous
//
#include <hip/hip_runtime.h>
#include <hip/hip_bf16.h>
#include <stdint.h>

#define K_D 512
#define N_C 100000
#define SCALE 64.0f

// margin constants (double-precision derived)
#define COS_M 0.87758256189037271612f
#define SIN_M 0.47942553860420300027f
#define TH   (-0.87758256189037271612f)
#define MM_C  0.23971276930210150013f

typedef __attribute__((ext_vector_type(8))) short bf16x8;
typedef __attribute__((ext_vector_type(4))) float f32x4;

#define NNB 782          // n-blocks of 128 classes (782*128 = 100096)
#define GZ_GRID 3128     // 782*4 = 8 XCDs x 391 exactly (bijective swizzle)
#define ZSTRIDE 784

// ws byte offsets (total 1,073,152 — within proven ws capacity >= 1,879,040)
#define OFF_INVNE 0          // 256 f
#define OFF_EMB   1024       // 256*512 ushorts = 262144 (fragment-ordered)
#define OFF_TP    263168     // 768*2 f
#define OFF_ZROW  269312     // 256 f
#define OFF_ZPART 270336     // 256*784 f = 802,816

__device__ __forceinline__ ushort f2bf(float f) {
    __hip_bfloat16 h = __float2bfloat16(f);
    return __builtin_bit_cast(ushort, h);
}

__device__ __forceinline__ void async16(const void* src, void* dst) {
    __builtin_amdgcn_global_load_lds(
        (const __attribute__((address_space(1))) void*)src,
        (__attribute__((address_space(3))) void*)dst,
        16, 0, 0);
}

// ---------------- prep_emb: fragment-ordered bf16 copy of E + inv row norms ----
// Ebf slot = ((row>>4)*16 + ks)*64 + (row&15) + g*16  (8 ushorts per slot):
// the A-frag load for (m-tile, ks) is one coalesced 1KB b128 load per wave.
__global__ __launch_bounds__(256) void prep_emb(const float* __restrict__ E,
                                                ushort* __restrict__ Ebf,
                                                float* __restrict__ invne) {
    int w = threadIdx.x >> 6, lane = threadIdx.x & 63;
    int row = blockIdx.x * 4 + w;
    const float4* src = (const float4*)(E + (size_t)row * K_D);
    float4 a = src[2 * lane];          // k = lane*8 .. +4
    float4 b = src[2 * lane + 1];      // k = lane*8+4 .. +8
    float ss = a.x*a.x + a.y*a.y + a.z*a.z + a.w*a.w
             + b.x*b.x + b.y*b.y + b.z*b.z + b.w*b.w;
    #pragma unroll
    for (int m = 32; m >= 1; m >>= 1) ss += __shfl_xor(ss, m, 64);
    uint4 pk;
    pk.x = (uint32_t)f2bf(a.x) | ((uint32_t)f2bf(a.y) << 16);
    pk.y = (uint32_t)f2bf(a.z) | ((uint32_t)f2bf(a.w) << 16);
    pk.z = (uint32_t)f2bf(b.x) | ((uint32_t)f2bf(b.y) << 16);
    pk.w = (uint32_t)f2bf(b.z) | ((uint32_t)f2bf(b.w) << 16);
    const int kstep = lane >> 2, gg = lane & 3;
    const size_t slot = ((size_t)(row >> 4) * 16 + kstep) * 64 + (row & 15) + (gg << 4);
    ((uint4*)Ebf)[slot] = pk;
    if (lane == 0) invne[row] = rsqrtf(ss + 1e-12f);
}

// ---------------- threefry2x32 (JAX, key=42) ----------------
__device__ __forceinline__ void threefry(uint32_t x0, uint32_t x1, uint32_t& o0, uint32_t& o1) {
    const uint32_t k0 = 0u, k1 = 42u;
    const uint32_t k2 = k0 ^ k1 ^ 0x1BD11BDAu;
    const uint32_t ks[3] = {k0, k1, k2};
    x0 += k0; x1 += k1;
    const int rot0[4] = {13, 15, 26, 6};
    const int rot1[4] = {17, 29, 16, 24};
    #pragma unroll
    for (int grp = 0; grp < 5; ++grp) {
        const int* r = (grp & 1) ? rot1 : rot0;
        #pragma unroll
        for (int i = 0; i < 4; ++i) {
            x0 += x1;
            x1 = (x1 << r[i]) | (x1 >> (32 - r[i]));
            x1 ^= x0;
        }
        x0 += ks[(grp + 1) % 3];
        x1 += ks[(grp + 2) % 3] + (uint32_t)(grp + 1);
    }
    o0 = x0; o1 = x1;
}

// ---------------- targets: inline label shuffle + precise fp32 cosine + margin ----
__global__ __launch_bounds__(256) void target_kernel(const float* __restrict__ E,
                                                     const float* __restrict__ W,
                                                     const int* __restrict__ ll,
                                                     float* __restrict__ tp) {
    int w = threadIdx.x >> 6, lane = threadIdx.x & 63;
    int p = blockIdx.x * 4 + w;      // 768 pairs
    int b = p / 3;
    int jj = p - b * 3;
    float u[8];
    #pragma unroll
    for (int j = 0; j < 8; ++j) {
        int n = b * 8 + j;
        uint32_t x0, x1, o0, o1;
        if (n < 1024) { x0 = (uint32_t)n; x1 = (uint32_t)(n + 1024); }
        else          { x0 = (uint32_t)(n - 1024); x1 = (uint32_t)n; }
        threefry(x0, x1, o0, o1);
        uint32_t bits = (n < 1024) ? o0 : o1;
        uint32_t fb = (bits >> 9) | 0x3F800000u;
        u[j] = __builtin_bit_cast(float, fb) - 1.0f;
    }
    bool used[8] = {false,false,false,false,false,false,false,false};
    int sel = 0;
    for (int s = 0; s <= jj; ++s) {
        float bv = 2.0f; int bi = 0;
        for (int i = 0; i < 8; ++i)
            if (!used[i] && u[i] < bv) { bv = u[i]; bi = i; }
        used[bi] = true;
        sel = bi;
    }
    int c = ll[b * 8 + sel];

    const float4* ep = (const float4*)(E + (size_t)b * K_D);
    const float4* wp = (const float4*)(W + (size_t)c * K_D);
    float4 e0 = ep[lane], e1 = ep[lane + 64];
    float4 w0 = wp[lane], w1 = wp[lane + 64];
    float dot = e0.x*w0.x + e0.y*w0.y + e0.z*w0.z + e0.w*w0.w
              + e1.x*w1.x + e1.y*w1.y + e1.z*w1.z + e1.w*w1.w;
    float esq = e0.x*e0.x + e0.y*e0.y + e0.z*e0.z + e0.w*e0.w
              + e1.x*e1.x + e1.y*e1.y + e1.z*e1.z + e1.w*e1.w;
    float wsq = w0.x*w0.x + w0.y*w0.y + w0.z*w0.z + w0.w*w0.w
              + w1.x*w1.x + w1.y*w1.y + w1.z*w1.z + w1.w*w1.w;
    #pragma unroll
    for (int m = 32; m >= 1; m >>= 1) {
        dot += __shfl_xor(dot, m, 64);
        esq += __shfl_xor(esq, m, 64);
        wsq += __shfl_xor(wsq, m, 64);
    }
    if (lane == 0) {
        float t = dot * rsqrtf(esq + 1e-12f) * rsqrtf(wsq + 1e-12f);
        t = fminf(1.0f, fmaxf(-1.0f, t));
        float tc = fminf(1.0f - 1e-7f, fmaxf(-1.0f + 1e-7f, t));
        float marg = tc * COS_M - sqrtf(fmaxf(0.0f, 1.0f - tc * tc)) * SIN_M;
        float ft = (t > TH) ? marg : (t - MM_C);
        tp[p * 2]     = t;
        tp[p * 2 + 1] = ft;
    }
}

// ---------------- fused GEMM + exp-sum ----------------
// 512 thr / 8 waves; block tile M=64 x N=128; wave = M=64 x N=16 (acc = 4 named
// f32x4). A staged once in LDS; W streamed to regs through a STATIC 4-deep
// prefetch ring (6 dwordx4 perpetually in flight per lane), no K-loop barriers.
// Bijective XCD swizzle keeps the 4 m-blocks of one n-strip on one XCD's L2.
__global__ __launch_bounds__(512, 4) void gemm_z(const float* __restrict__ W,
                                                 const ushort* __restrict__ Ebf,
                                                 const float* __restrict__ invne,
                                                 float* __restrict__ zpart) {
    __shared__ ushort Als[64 * 512];   // 64 KB, fragment-ordered
    __shared__ float zred[64 * 8];

    const int tid  = threadIdx.x;
    const int lane = tid & 63, wv = tid >> 6;   // wv 0..7
    const int r16  = lane & 15, g = lane >> 4;

    const int wid = (blockIdx.x & 7) * 391 + (blockIdx.x >> 3);
    const int nb  = wid >> 2;          // 0..781
    const int mb  = wid & 3;           // 0..3
    const int c0  = nb * 128;
    const int r0  = mb * 64;

    // stage A: 64 KB linear DMA from Ebf (frag-ordered, rows r0..r0+63)
    {
        const ushort* src = Ebf + (size_t)r0 * K_D + (size_t)wv * (8 * 512) + lane * 8;
        #pragma unroll
        for (int t = 0; t < 8; ++t)
            async16(src + t * 512, &Als[(wv * 8 + t) * 512]);
    }
    __syncthreads();

    const int ccls = c0 + wv * 16 + r16;               // this lane's class
    const int ccl  = ccls < N_C ? ccls : N_C - 1;
    const float4* wr = (const float4*)(W + (size_t)ccl * K_D + g * 8);
    // W data for step ks lives at wr[ks*8], wr[ks*8+1]

    f32x4 acc0 = {}, acc1 = {}, acc2 = {}, acc3 = {};
    float ssq = 0.f;

    // 4-deep static prefetch ring
    float4 p0a = wr[0],  p0b = wr[1];
    float4 p1a = wr[8],  p1b = wr[9];
    float4 p2a = wr[16], p2b = wr[17];
    float4 p3a = wr[24], p3b = wr[25];

    #define KSTEP(KS, PA, PB)                                                   \
        {                                                                       \
            float4 fa = PA, fb = PB;                                            \
            if ((KS) + 4 < 16) {                                                \
                PA = wr[((KS) + 4) * 8];                                        \
                PB = wr[((KS) + 4) * 8 + 1];                                    \
            }                                                                   \
            ssq += fa.x*fa.x + fa.y*fa.y + fa.z*fa.z + fa.w*fa.w                \
                 + fb.x*fb.x + fb.y*fb.y + fb.z*fb.z + fb.w*fb.w;               \
            bf16x8 bv;                                                          \
            bv[0] = (short)f2bf(fa.x); bv[1] = (short)f2bf(fa.y);               \
            bv[2] = (short)f2bf(fa.z); bv[3] = (short)f2bf(fa.w);               \
            bv[4] = (short)f2bf(fb.x); bv[5] = (short)f2bf(fb.y);               \
            bv[6] = (short)f2bf(fb.z); bv[7] = (short)f2bf(fb.w);               \
            const int ao = (KS) * 512 + lane * 8;                               \
            acc0 = __builtin_amdgcn_mfma_f32_16x16x32_bf16(                     \
                       *(const bf16x8*)&Als[ao],          bv, acc0, 0, 0, 0);   \
            acc1 = __builtin_amdgcn_mfma_f32_16x16x32_bf16(                     \
                       *(const bf16x8*)&Als[ao + 8192],   bv, acc1, 0, 0, 0);   \
            acc2 = __builtin_amdgcn_mfma_f32_16x16x32_bf16(                     \
                       *(const bf16x8*)&Als[ao + 16384],  bv, acc2, 0, 0, 0);   \
            acc3 = __builtin_amdgcn_mfma_f32_16x16x32_bf16(                     \
                       *(const bf16x8*)&Als[ao + 24576],  bv, acc3, 0, 0, 0);   \
        }

    #pragma unroll
    for (int kq = 0; kq < 4; ++kq) {
        KSTEP(kq * 4 + 0, p0a, p0b);
        KSTEP(kq * 4 + 1, p1a, p1b);
        KSTEP(kq * 4 + 2, p2a, p2b);
        KSTEP(kq * 4 + 3, p3a, p3b);
    }
    #undef KSTEP

    // class inverse norm: reduce ssq over the 4 g-groups (same class)
    float sr = ssq;
    sr += __shfl_xor(sr, 16, 64);
    sr += __shfl_xor(sr, 32, 64);
    const float inw = rsqrtf(sr + 1e-12f);
    const bool valid = ccls < N_C;

    // epilogue: cos -> exp(64cos-64); reduce over this wave's 16 classes
    #define EPI(MT, ACC)                                                        \
        _Pragma("unroll")                                                       \
        for (int i = 0; i < 4; ++i) {                                           \
            const int rloc = (MT) * 16 + g * 4 + i;                             \
            float cv = ACC[i] * inw * invne[r0 + rloc];                         \
            cv = fminf(1.0f, fmaxf(-1.0f, cv));                                 \
            float s = valid ? __expf(SCALE * cv - 64.0f) : 0.f;                 \
            s += __shfl_xor(s, 1, 64);                                          \
            s += __shfl_xor(s, 2, 64);                                          \
            s += __shfl_xor(s, 4, 64);                                          \
            s += __shfl_xor(s, 8, 64);                                          \
            if (r16 == 0) zred[rloc * 8 + wv] = s;                              \
        }
    EPI(0, acc0)
    EPI(1, acc1)
    EPI(2, acc2)
    EPI(3, acc3)
    #undef EPI

    __syncthreads();
    // cross-wave: 64 rows x 8 wave-partials, deterministic order
    if (tid < 64) {
        float t = 0.f;
        #pragma unroll
        for (int v = 0; v < 8; ++v) t += zred[tid * 8 + v];
        zpart[(size_t)(r0 + tid) * ZSTRIDE + nb] = t;
    }
}

// ---------------- per-row Z reduction (coalesced) ----------------
__global__ __launch_bounds__(256) void zrow_kernel(const float* __restrict__ zpart,
                                                   float* __restrict__ zrow) {
    const int b = blockIdx.x;
    float sum = 0.f;
    for (int t = threadIdx.x; t < NNB; t += 256)
        sum += zpart[(size_t)b * ZSTRIDE + t];
    __shared__ float red[256];
    red[threadIdx.x] = sum;
    __syncthreads();
    for (int st = 128; st >= 1; st >>= 1) {
        if (threadIdx.x < st) red[threadIdx.x] += red[threadIdx.x + st];
        __syncthreads();
    }
    if (threadIdx.x == 0) zrow[b] = red[0];
}

// ---------------- final loss ----------------
__global__ __launch_bounds__(256) void loss_kernel(const float* __restrict__ zrow,
                                                   const float* __restrict__ tp,
                                                   float* __restrict__ out) {
    const int b = threadIdx.x;
    const float Z = zrow[b];
    float lsum = 0.f;
    #pragma unroll
    for (int j = 0; j < 3; ++j) {
        float t  = tp[(b * 3 + j) * 2];
        float ft = tp[(b * 3 + j) * 2 + 1];
        float S = Z - expf(SCALE * t - 64.0f) + expf(SCALE * ft - 64.0f);
        lsum += logf(S) + 64.0f - SCALE * ft;
    }
    __shared__ float red[256];
    red[b] = lsum;
    __syncthreads();
    for (int st = 128; st >= 1; st >>= 1) {
        if (b < st) red[b] += red[b + st];
        __syncthreads();
    }
    if (b == 0) out[0] = red[0] / 768.0f;
}

extern "C" void kernel_launch(void* const* d_in, const int* in_sizes, int n_in,
                              void* d_out, int out_size, void* d_ws, size_t ws_size,
                              hipStream_t stream) {
    const float* E = (const float*)d_in[0];
    const float* W = (const float*)d_in[1];
    const int*  LL = (const int*)d_in[2];
    char* ws = (char*)d_ws;
    float*  invne = (float*)(ws + OFF_INVNE);
    ushort* Ebf   = (ushort*)(ws + OFF_EMB);
    float*  tp    = (float*)(ws + OFF_TP);
    float*  zrow  = (float*)(ws + OFF_ZROW);
    float*  zpart = (float*)(ws + OFF_ZPART);
    float*  out   = (float*)d_out;

    hipLaunchKernelGGL(prep_emb,      dim3(64),      dim3(256), 0, stream, E, Ebf, invne);
    hipLaunchKernelGGL(target_kernel, dim3(192),     dim3(256), 0, stream, E, W, LL, tp);
    hipLaunchKernelGGL(gemm_z,        dim3(GZ_GRID), dim3(512), 0, stream, W, Ebf, invne, zpart);
    hipLaunchKernelGGL(zrow_kernel,   dim3(256),     dim3(256), 0, stream, zpart, zrow);
    hipLaunchKernelGGL(loss_kernel,   dim3(1),       dim3(256), 0, stream, zrow, tp, out);
}

// Round 7
// 99.130 us; speedup vs baseline: 4.1086x; 1.4326x over previous
//
#include <hip/hip_runtime.h>
#include <hip/hip_bf16.h>
#include <stdint.h>

#define K_D 512
#define N_C 100000
#define SCALE 64.0f

// margin constants (double-precision derived)
#define COS_M 0.87758256189037271612f
#define SIN_M 0.47942553860420300027f
#define TH   (-0.87758256189037271612f)
#define MM_C  0.23971276930210150013f

typedef __attribute__((ext_vector_type(8))) short bf16x8;
typedef __attribute__((ext_vector_type(4))) float f32x4;

#define GZ_BLOCKS 1250   // x 5 chunks x 16 classes = 100,000 exactly
#define CHUNKS_PB 5
#define ZSTRIDE 1280
#define ROWF 516         // padded LDS row stride (129 float4 -> conflict-free)

// ws byte offsets (end 1,581,056 — within proven ws capacity >= 1,879,040)
#define OFF_INVNE 0          // 256 f
#define OFF_EMB   1024       // 256*512 ushorts = 262144 (fragment-ordered)
#define OFF_TP    263168     // 768*2 f
#define OFF_ZROW  269312     // 256 f
#define OFF_ZPART 270336     // 256*1280 f = 1,310,720

__device__ __forceinline__ ushort f2bf(float f) {
    __hip_bfloat16 h = __float2bfloat16(f);
    return __builtin_bit_cast(ushort, h);
}

__device__ __forceinline__ void async16(const void* src, void* dst) {
    __builtin_amdgcn_global_load_lds(
        (const __attribute__((address_space(1))) void*)src,
        (__attribute__((address_space(3))) void*)dst,
        16, 0, 0);
}

// ---------------- prep_emb: fragment-ordered bf16 copy of E + inv row norms ----
// Ebf slot = ((row>>4)*16 + ks)*64 + (row&15) + g*16  (8 ushorts per slot):
// the A-frag load for (m-tile, ks) is one coalesced 1KB b128 load per wave.
__global__ __launch_bounds__(256) void prep_emb(const float* __restrict__ E,
                                                ushort* __restrict__ Ebf,
                                                float* __restrict__ invne) {
    int w = threadIdx.x >> 6, lane = threadIdx.x & 63;
    int row = blockIdx.x * 4 + w;
    const float4* src = (const float4*)(E + (size_t)row * K_D);
    float4 a = src[2 * lane];          // k = lane*8 .. +4
    float4 b = src[2 * lane + 1];      // k = lane*8+4 .. +8
    float ss = a.x*a.x + a.y*a.y + a.z*a.z + a.w*a.w
             + b.x*b.x + b.y*b.y + b.z*b.z + b.w*b.w;
    #pragma unroll
    for (int m = 32; m >= 1; m >>= 1) ss += __shfl_xor(ss, m, 64);
    uint4 pk;
    pk.x = (uint32_t)f2bf(a.x) | ((uint32_t)f2bf(a.y) << 16);
    pk.y = (uint32_t)f2bf(a.z) | ((uint32_t)f2bf(a.w) << 16);
    pk.z = (uint32_t)f2bf(b.x) | ((uint32_t)f2bf(b.y) << 16);
    pk.w = (uint32_t)f2bf(b.z) | ((uint32_t)f2bf(b.w) << 16);
    const int kstep = lane >> 2, gg = lane & 3;
    const size_t slot = ((size_t)(row >> 4) * 16 + kstep) * 64 + (row & 15) + (gg << 4);
    ((uint4*)Ebf)[slot] = pk;
    if (lane == 0) invne[row] = rsqrtf(ss + 1e-12f);
}

// ---------------- threefry2x32 (JAX, key=42) ----------------
__device__ __forceinline__ void threefry(uint32_t x0, uint32_t x1, uint32_t& o0, uint32_t& o1) {
    const uint32_t k0 = 0u, k1 = 42u;
    const uint32_t k2 = k0 ^ k1 ^ 0x1BD11BDAu;
    const uint32_t ks[3] = {k0, k1, k2};
    x0 += k0; x1 += k1;
    const int rot0[4] = {13, 15, 26, 6};
    const int rot1[4] = {17, 29, 16, 24};
    #pragma unroll
    for (int grp = 0; grp < 5; ++grp) {
        const int* r = (grp & 1) ? rot1 : rot0;
        #pragma unroll
        for (int i = 0; i < 4; ++i) {
            x0 += x1;
            x1 = (x1 << r[i]) | (x1 >> (32 - r[i]));
            x1 ^= x0;
        }
        x0 += ks[(grp + 1) % 3];
        x1 += ks[(grp + 2) % 3] + (uint32_t)(grp + 1);
    }
    o0 = x0; o1 = x1;
}

// ---------------- targets: inline label shuffle + precise fp32 cosine + margin ----
__global__ __launch_bounds__(256) void target_kernel(const float* __restrict__ E,
                                                     const float* __restrict__ W,
                                                     const int* __restrict__ ll,
                                                     float* __restrict__ tp) {
    int w = threadIdx.x >> 6, lane = threadIdx.x & 63;
    int p = blockIdx.x * 4 + w;      // 768 pairs
    int b = p / 3;
    int jj = p - b * 3;
    float u[8];
    #pragma unroll
    for (int j = 0; j < 8; ++j) {
        int n = b * 8 + j;
        uint32_t x0, x1, o0, o1;
        if (n < 1024) { x0 = (uint32_t)n; x1 = (uint32_t)(n + 1024); }
        else          { x0 = (uint32_t)(n - 1024); x1 = (uint32_t)n; }
        threefry(x0, x1, o0, o1);
        uint32_t bits = (n < 1024) ? o0 : o1;
        uint32_t fb = (bits >> 9) | 0x3F800000u;
        u[j] = __builtin_bit_cast(float, fb) - 1.0f;
    }
    bool used[8] = {false,false,false,false,false,false,false,false};
    int sel = 0;
    for (int s = 0; s <= jj; ++s) {
        float bv = 2.0f; int bi = 0;
        for (int i = 0; i < 8; ++i)
            if (!used[i] && u[i] < bv) { bv = u[i]; bi = i; }
        used[bi] = true;
        sel = bi;
    }
    int c = ll[b * 8 + sel];

    const float4* ep = (const float4*)(E + (size_t)b * K_D);
    const float4* wp = (const float4*)(W + (size_t)c * K_D);
    float4 e0 = ep[lane], e1 = ep[lane + 64];
    float4 w0 = wp[lane], w1 = wp[lane + 64];
    float dot = e0.x*w0.x + e0.y*w0.y + e0.z*w0.z + e0.w*w0.w
              + e1.x*w1.x + e1.y*w1.y + e1.z*w1.z + e1.w*w1.w;
    float esq = e0.x*e0.x + e0.y*e0.y + e0.z*e0.z + e0.w*e0.w
              + e1.x*e1.x + e1.y*e1.y + e1.z*e1.z + e1.w*e1.w;
    float wsq = w0.x*w0.x + w0.y*w0.y + w0.z*w0.z + w0.w*w0.w
              + w1.x*w1.x + w1.y*w1.y + w1.z*w1.z + w1.w*w1.w;
    #pragma unroll
    for (int m = 32; m >= 1; m >>= 1) {
        dot += __shfl_xor(dot, m, 64);
        esq += __shfl_xor(esq, m, 64);
        wsq += __shfl_xor(wsq, m, 64);
    }
    if (lane == 0) {
        float t = dot * rsqrtf(esq + 1e-12f) * rsqrtf(wsq + 1e-12f);
        t = fminf(1.0f, fmaxf(-1.0f, t));
        float tc = fminf(1.0f - 1e-7f, fmaxf(-1.0f + 1e-7f, t));
        float marg = tc * COS_M - sqrtf(fmaxf(0.0f, 1.0f - tc * tc)) * SIN_M;
        float ft = (t > TH) ? marg : (t - MM_C);
        tp[p * 2]     = t;
        tp[p * 2 + 1] = ft;
    }
}

// ---------------- fused GEMM + exp-sum: DMA chunks + counted-vmcnt pipeline ----
// 512 thr / 8 waves; block owns 80 classes (5 chunks of 16 full W rows).
// Per chunk: issue next chunk's DMA (4 x 1KB per wave), s_waitcnt vmcnt(4)
// (current chunk landed; NEXT chunk's loads stay in flight across the raw
// s_barrier), full K=512 MFMA pass, raw s_barrier. No vmcnt(0) in the loop.
// LDS rows padded to 516 floats -> quarter-wave b128 reads are 2-way (free).
__global__ __launch_bounds__(512, 4) void gemm_z(const float* __restrict__ W,
                                                 const ushort* __restrict__ Ebf,
                                                 const float* __restrict__ invne,
                                                 float* __restrict__ zpart) {
    __shared__ float Wb[2][16 * ROWF];   // 2 x 33 KB, padded rows
    __shared__ float ine_lds[256];

    const int tid  = threadIdx.x;
    const int lane = tid & 63, wv = tid >> 6;       // wv 0..7
    const int r16  = lane & 15, g = lane >> 4;
    const int bx   = blockIdx.x;
    const int cbase = bx * (16 * CHUNKS_PB);

    if (tid < 256) ine_lds[tid] = invne[tid];

    // wave wv stages rows wv*2, wv*2+1 of a chunk: 4 x (1KB contiguous) DMA
    #define STAGE(ch, b)                                                        \
        {                                                                       \
            _Pragma("unroll")                                                   \
            for (int rr = 0; rr < 2; ++rr) {                                    \
                const int r = wv * 2 + rr;                                      \
                const float* src = W + (size_t)(cbase + (ch) * 16 + r) * K_D    \
                                     + lane * 4;                                \
                async16(src,        &Wb[b][r * ROWF]);                          \
                async16(src + 256,  &Wb[b][r * ROWF + 256]);                    \
            }                                                                   \
        }

    STAGE(0, 0);

    const ushort* ap0 = Ebf + ((size_t)(wv * 2 + 0) * 16) * 64 * 8 + lane * 8;
    const ushort* ap1 = Ebf + ((size_t)(wv * 2 + 1) * 16) * 64 * 8 + lane * 8;

    float zacc[2][4] = {};

    for (int ch = 0; ch < CHUNKS_PB; ++ch) {
        const int cur = ch & 1;
        if (ch + 1 < CHUNKS_PB) {
            STAGE(ch + 1, cur ^ 1);
            asm volatile("s_waitcnt vmcnt(4)" ::: "memory");
        } else {
            asm volatile("s_waitcnt vmcnt(0)" ::: "memory");
        }
        __builtin_amdgcn_s_barrier();          // chunk ch fully in LDS
        __builtin_amdgcn_sched_barrier(0);

        f32x4 acc0 = {}, acc1 = {};
        float ssq = 0.f;
        const float4* bp = (const float4*)&Wb[cur][r16 * ROWF];

        #pragma unroll 4
        for (int ks = 0; ks < 16; ++ks) {
            bf16x8 a0 = *(const bf16x8*)(ap0 + (size_t)ks * 512);
            bf16x8 a1 = *(const bf16x8*)(ap1 + (size_t)ks * 512);
            float4 f0 = bp[ks * 8 + g * 2];
            float4 f1 = bp[ks * 8 + g * 2 + 1];
            ssq += f0.x*f0.x + f0.y*f0.y + f0.z*f0.z + f0.w*f0.w
                 + f1.x*f1.x + f1.y*f1.y + f1.z*f1.z + f1.w*f1.w;
            bf16x8 bv;
            bv[0] = (short)f2bf(f0.x); bv[1] = (short)f2bf(f0.y);
            bv[2] = (short)f2bf(f0.z); bv[3] = (short)f2bf(f0.w);
            bv[4] = (short)f2bf(f1.x); bv[5] = (short)f2bf(f1.y);
            bv[6] = (short)f2bf(f1.z); bv[7] = (short)f2bf(f1.w);
            acc0 = __builtin_amdgcn_mfma_f32_16x16x32_bf16(a0, bv, acc0, 0, 0, 0);
            acc1 = __builtin_amdgcn_mfma_f32_16x16x32_bf16(a1, bv, acc1, 0, 0, 0);
        }

        // class inverse norm (class = cbase + ch*16 + r16): reduce ssq over g
        float sr = ssq;
        sr += __shfl_xor(sr, 16, 64);
        sr += __shfl_xor(sr, 32, 64);
        const float inw = rsqrtf(sr + 1e-12f);

        #pragma unroll
        for (int i = 0; i < 4; ++i) {
            const int row0 = (wv * 2 + 0) * 16 + g * 4 + i;
            const int row1 = (wv * 2 + 1) * 16 + g * 4 + i;
            float c0 = acc0[i] * inw * ine_lds[row0];
            float c1 = acc1[i] * inw * ine_lds[row1];
            c0 = fminf(1.0f, fmaxf(-1.0f, c0));
            c1 = fminf(1.0f, fmaxf(-1.0f, c1));
            zacc[0][i] += __expf(SCALE * c0 - 64.0f);
            zacc[1][i] += __expf(SCALE * c1 - 64.0f);
        }
        __builtin_amdgcn_s_barrier();          // all waves done reading buf cur
    }

    // reduce zacc over the 16 classes (r16 lanes), write zpart[row][bx]
    #pragma unroll
    for (int mi = 0; mi < 2; ++mi)
        #pragma unroll
        for (int i = 0; i < 4; ++i) {
            float v = zacc[mi][i];
            v += __shfl_xor(v, 1, 64);
            v += __shfl_xor(v, 2, 64);
            v += __shfl_xor(v, 4, 64);
            v += __shfl_xor(v, 8, 64);
            if (r16 == 0) {
                const int row = (wv * 2 + mi) * 16 + g * 4 + i;
                zpart[(size_t)row * ZSTRIDE + bx] = v;
            }
        }
}

// ---------------- per-row Z reduction (coalesced) ----------------
__global__ __launch_bounds__(256) void zrow_kernel(const float* __restrict__ zpart,
                                                   float* __restrict__ zrow) {
    const int b = blockIdx.x;
    float sum = 0.f;
    for (int t = threadIdx.x; t < GZ_BLOCKS; t += 256)
        sum += zpart[(size_t)b * ZSTRIDE + t];
    __shared__ float red[256];
    red[threadIdx.x] = sum;
    __syncthreads();
    for (int st = 128; st >= 1; st >>= 1) {
        if (threadIdx.x < st) red[threadIdx.x] += red[threadIdx.x + st];
        __syncthreads();
    }
    if (threadIdx.x == 0) zrow[b] = red[0];
}

// ---------------- final loss ----------------
__global__ __launch_bounds__(256) void loss_kernel(const float* __restrict__ zrow,
                                                   const float* __restrict__ tp,
                                                   float* __restrict__ out) {
    const int b = threadIdx.x;
    const float Z = zrow[b];
    float lsum = 0.f;
    #pragma unroll
    for (int j = 0; j < 3; ++j) {
        float t  = tp[(b * 3 + j) * 2];
        float ft = tp[(b * 3 + j) * 2 + 1];
        float S = Z - expf(SCALE * t - 64.0f) + expf(SCALE * ft - 64.0f);
        lsum += logf(S) + 64.0f - SCALE * ft;
    }
    __shared__ float red[256];
    red[b] = lsum;
    __syncthreads();
    for (int st = 128; st >= 1; st >>= 1) {
        if (b < st) red[b] += red[b + st];
        __syncthreads();
    }
    if (b == 0) out[0] = red[0] / 768.0f;
}

extern "C" void kernel_launch(void* const* d_in, const int* in_sizes, int n_in,
                              void* d_out, int out_size, void* d_ws, size_t ws_size,
                              hipStream_t stream) {
    const float* E = (const float*)d_in[0];
    const float* W = (const float*)d_in[1];
    const int*  LL = (const int*)d_in[2];
    char* ws = (char*)d_ws;
    float*  invne = (float*)(ws + OFF_INVNE);
    ushort* Ebf   = (ushort*)(ws + OFF_EMB);
    float*  tp    = (float*)(ws + OFF_TP);
    float*  zrow  = (float*)(ws + OFF_ZROW);
    float*  zpart = (float*)(ws + OFF_ZPART);
    float*  out   = (float*)d_out;

    hipLaunchKernelGGL(prep_emb,      dim3(64),        dim3(256), 0, stream, E, Ebf, invne);
    hipLaunchKernelGGL(target_kernel, dim3(192),       dim3(256), 0, stream, E, W, LL, tp);
    hipLaunchKernelGGL(gemm_z,        dim3(GZ_BLOCKS), dim3(512), 0, stream, W, Ebf, invne, zpart);
    hipLaunchKernelGGL(zrow_kernel,   dim3(256),       dim3(256), 0, stream, zpart, zrow);
    hipLaunchKernelGGL(loss_kernel,   dim3(1),         dim3(256), 0, stream, zrow, tp, out);
}